// Round 13
// baseline (168.456 us; speedup 1.0000x reference)
//
#include <hip/hip_runtime.h>
#include <hip/hip_bf16.h>

#define SEQ 2048
#define DIMM 2048
#define NQH 32
#define NKVH 8
#define HD 64

typedef _Float16 half8 __attribute__((ext_vector_type(8)));
typedef float f32x4 __attribute__((ext_vector_type(4)));
using fp16 = _Float16;

typedef __attribute__((address_space(1))) unsigned int ga_u32;
typedef __attribute__((address_space(3))) unsigned int ls_u32;

__device__ __forceinline__ void gll16(const void* g, void* l) {
    __builtin_amdgcn_global_load_lds((const ga_u32*)g, (ls_u32*)l, 16, 0, 0);
}

// ---------------- cast fp32 -> fp16 (vectorized) ----------------
__global__ void cast_f32_f16(const float* __restrict__ in, fp16* __restrict__ out, int n) {
    int i = (blockIdx.x * 256 + threadIdx.x) * 4;
    if (i < n) {
        float4 v = *reinterpret_cast<const float4*>(in + i);
#pragma unroll
        for (int j = 0; j < 4; j++) out[i + j] = (fp16)(&v.x)[j];
    }
}

// ------------- fused weight transpose: wq/wk/wv fp32 [head][2048][64] -> wqkvt fp16 [48][64][2048] -------------
__global__ void transpose_qkvw(const float* __restrict__ wq, const float* __restrict__ wk,
                               const float* __restrict__ wv, fp16* __restrict__ out) {
    __shared__ float tile[64][65];
    const int z = blockIdx.z;
    const float* inh = (z < 32) ? wq + (size_t)z * SEQ * HD
                                : (z < 40) ? wk + (size_t)(z - 32) * SEQ * HD
                                           : wv + (size_t)(z - 40) * SEQ * HD;
    fp16* outh = out + (size_t)z * HD * SEQ;
    int r0 = blockIdx.x * 64;
    int t = threadIdx.x;
#pragma unroll
    for (int i = 0; i < 16; i++) {
        int idx = i * 256 + t;
        int r = idx >> 6, c = idx & 63;
        tile[r][c] = inh[(size_t)(r0 + r) * HD + c];
    }
    __syncthreads();
#pragma unroll
    for (int i = 0; i < 16; i++) {
        int idx = i * 256 + t;
        int cc = idx >> 6, rr = idx & 63;
        outh[(size_t)cc * SEQ + r0 + rr] = (fp16)tile[rr][cc];
    }
}

// ------------- tiled transpose + cast: in fp32 [R][C] -> out fp16 [C][R] (for w_out) -------------
__global__ void transpose_cast(const float* __restrict__ in, fp16* __restrict__ out, int R, int C) {
    __shared__ float tile[64][65];
    int r0 = blockIdx.x * 64, c0 = blockIdx.y * 64;
    int t = threadIdx.x;
#pragma unroll
    for (int i = 0; i < 16; i++) {
        int idx = i * 256 + t;
        int r = idx >> 6, c = idx & 63;
        tile[r][c] = in[(size_t)(r0 + r) * C + c0 + c];
    }
    __syncthreads();
#pragma unroll
    for (int i = 0; i < 16; i++) {
        int idx = i * 256 + t;
        int cc = idx >> 6, rr = idx & 63;
        out[(size_t)(c0 + cc) * R + r0 + rr] = (fp16)tile[rr][cc];
    }
}

// ---------------- fused RoPE + V-transpose (both read proj[2048][3072]) ----------------
__global__ void rope_vt_kernel(const fp16* __restrict__ proj, fp16* __restrict__ qb,
                               fp16* __restrict__ kb, fp16* __restrict__ vtb) {
    __shared__ fp16 tile[64][72];
    const int bx = blockIdx.x;
    if (bx < 10240) {
        int tid = bx * 256 + threadIdx.x;  // 40*2048*32
        int pair = tid & 31;
        int s = (tid >> 5) & 2047;
        int head = tid >> 16;
        const fp16* src = proj + (size_t)s * 3072 + head * HD + 2 * pair;
        float x1 = (float)src[0];
        float x2 = (float)src[1];
        float invf = expf(-((float)pair / 32.0f) * 9.210340371976184f);  // 10000^(-2j/64)
        float ang = (float)s * invf;
        float sn, cs;
        sincosf(ang, &sn, &cs);
        float o1 = cs * x1 - sn * x2;
        float o2 = sn * x1 + cs * x2;
        fp16* dst = (head < NQH) ? (qb + ((size_t)head * SEQ + s) * HD + 2 * pair)
                                 : (kb + ((size_t)(head - NQH) * SEQ + s) * HD + 2 * pair);
        dst[0] = (fp16)o1;
        dst[1] = (fp16)o2;
    } else {
        const int idx = bx - 10240;          // 0..255
        const int g = idx >> 5;              // kv group
        const int s0 = (idx & 31) * 64;      // seq tile
        const int t = threadIdx.x;
#pragma unroll
        for (int i = 0; i < 16; i++) {
            int id2 = i * 256 + t;
            int r = id2 >> 6, c = id2 & 63;
            tile[r][c] = proj[(size_t)(s0 + r) * 3072 + 2560 + g * HD + c];
        }
        __syncthreads();
#pragma unroll
        for (int i = 0; i < 16; i++) {
            int id2 = i * 256 + t;
            int cc = id2 >> 6, rr = id2 & 63;
            vtb[((size_t)g * HD + cc) * SEQ + s0 + rr] = tile[rr][cc];
        }
    }
}

// ============ GEMM core: 128x128 tile, BK=64, DOUBLE-BUFFERED gll staging, XOR swizzle ============
#define GEMM_CORE(A_, Bt_, K_)                                                              \
    __shared__ fp16 As[2][128][64];                                                         \
    __shared__ fp16 Bs[2][128][64];                                                         \
    const int t = threadIdx.x;                                                              \
    const int m0 = blockIdx.x * 128, n0 = blockIdx.y * 128;                                 \
    const int wid = t >> 6, lane = t & 63;                                                  \
    const int wm = (wid >> 1) * 64, wn = (wid & 1) * 64;                                    \
    const int lr = lane & 15, lg = lane >> 4;                                               \
    f32x4 acc[4][4] = {};                                                                   \
    const int nk = (K_) >> 6;                                                               \
    auto stage_ = [&](int kt, int b) {                                                      \
        _Pragma("unroll") for (int i = 0; i < 4; i++) {                                     \
            int s = i * 256 + t;                                                            \
            int row = s >> 3, ch = s & 7;                                                   \
            int lch = ch ^ (row & 7); /* pre-swizzled global source, linear LDS dest */     \
            gll16((A_) + (size_t)(m0 + row) * (K_) + (kt << 6) + lch * 8,                   \
                  (char*)&As[b][0][0] + s * 16);                                            \
            gll16((Bt_) + (size_t)(n0 + row) * (K_) + (kt << 6) + lch * 8,                  \
                  (char*)&Bs[b][0][0] + s * 16);                                            \
        }                                                                                   \
    };                                                                                      \
    stage_(0, 0);                                                                           \
    __syncthreads();                                                                        \
    for (int kt = 0; kt < nk; ++kt) {                                                       \
        const int cur = kt & 1;                                                             \
        if (kt + 1 < nk) stage_(kt + 1, cur ^ 1);                                           \
        _Pragma("unroll") for (int kk = 0; kk < 2; kk++) {                                  \
            half8 af[4], bfv[4];                                                            \
            _Pragma("unroll") for (int m = 0; m < 4; m++) {                                 \
                int row = wm + m * 16 + lr;                                                 \
                af[m] = *(const half8*)((const char*)&As[cur][row][0] + (((kk * 4 + lg) ^ (row & 7)) * 16)); \
            }                                                                               \
            _Pragma("unroll") for (int n = 0; n < 4; n++) {                                 \
                int row = wn + n * 16 + lr;                                                 \
                bfv[n] = *(const half8*)((const char*)&Bs[cur][row][0] + (((kk * 4 + lg) ^ (row & 7)) * 16)); \
            }                                                                               \
            __builtin_amdgcn_s_setprio(1);                                                  \
            _Pragma("unroll") for (int m = 0; m < 4; m++)                                   \
                _Pragma("unroll") for (int n = 0; n < 4; n++)                               \
                    acc[m][n] = __builtin_amdgcn_mfma_f32_16x16x32_f16(af[m], bfv[n], acc[m][n], 0, 0, 0); \
            __builtin_amdgcn_s_setprio(0);                                                  \
        }                                                                                   \
        __syncthreads(); /* vmcnt drained here -> next tile ready; protects buf reuse */    \
    }

// ---------------- QKV projection: proj[2048][3072] fp16, trivial epilogue ----------------
__global__ __launch_bounds__(256) void gemm_proj(
    const fp16* __restrict__ A, const fp16* __restrict__ Bt, fp16* __restrict__ Cout) {
    GEMM_CORE(A, Bt, 2048)
#pragma unroll
    for (int m = 0; m < 4; m++)
#pragma unroll
        for (int n = 0; n < 4; n++)
#pragma unroll
            for (int r = 0; r < 4; r++) {
                int row = m0 + wm + m * 16 + lg * 4 + r;
                int col = n0 + wn + n * 16 + lr;
                Cout[(size_t)row * 3072 + col] = (fp16)acc[m][n][r];
            }
}

// ---------------- out projection: C[2048][2048] fp32 ----------------
__global__ __launch_bounds__(256) void gemm_out2(
    const fp16* __restrict__ A, const fp16* __restrict__ Bt, float* __restrict__ Cout) {
    GEMM_CORE(A, Bt, 2048)
#pragma unroll
    for (int m = 0; m < 4; m++)
#pragma unroll
        for (int n = 0; n < 4; n++)
#pragma unroll
            for (int r = 0; r < 4; r++) {
                int row = m0 + wm + m * 16 + lg * 4 + r;
                int col = n0 + wn + n * 16 + lr;
                Cout[(size_t)row * 2048 + col] = acc[m][n][r];
            }
}

// ---------------- causal flash attention: uniform 16/17-tile blocks via one kv-split per pair ----
// grid (1024): head = bx&31; pr = bx>>5; p = pr&15 (pair {p, 31-p}); halfB = pr>>4.
//   A (halfB=0): qt=p full causal (p+1 tiles, direct write) THEN qt=31-p kv [0,15-p) partial slot 0.
//   B (halfB=1): qt=31-p kv [15-p,32-p) incl diagonal, partial slot 1.
// Partials LSE-normalized: part_o = o/lsum (fp16), part_mlog = m + log(lsum) (f32).
__global__ __launch_bounds__(256) void attn_kernel(
    const fp16* __restrict__ qb, const fp16* __restrict__ kb,
    const fp16* __restrict__ vt, fp16* __restrict__ o_all,
    fp16* __restrict__ part_o, float* __restrict__ part_mlog) {
    __shared__ fp16 Kb[2][64][64];  // 16 KB (16B-chunk XOR swizzled)
    __shared__ fp16 Vb[2][64][64];  // 16 KB (swizzled)
    __shared__ fp16 P[4][16][64];   //  8 KB (swizzled stride-64) -> 40960 B total
    const int t = threadIdx.x, wid = t >> 6, lane = t & 63;
    const int bx = blockIdx.x;
    const int head = bx & 31;
    const int pr = bx >> 5;
    const int p = pr & 15;
    const int halfB = pr >> 4;
    const int g = head >> 2;
    const int lr = lane & 15, lg = lane >> 4;
    const fp16* qh = qb + (size_t)head * SEQ * HD;
    const fp16* kh = kb + (size_t)g * SEQ * HD;
    const fp16* vh = vt + (size_t)g * HD * SEQ;
    const int srow = lane >> 3, schunk = lane & 7;

    auto stage = [&](int kt, int b) {
        const int kv0 = kt << 6;
#pragma unroll
        for (int i = 0; i < 2; ++i) {
            int row = wid * 16 + i * 8 + srow;
            int sw = (schunk ^ srow) * 8;
            gll16(kh + (size_t)(kv0 + row) * HD + sw, &Kb[b][wid * 16 + i * 8][0]);
            gll16(vh + (size_t)row * SEQ + kv0 + sw, &Vb[b][wid * 16 + i * 8][0]);
        }
    };

    // mode 0: direct o_all write. mode 1: LSE partial write to slot.
    auto run_range = [&](int qt, int t_lo, int t_hi, int mode, int slot) {
        __syncthreads();  // protect LDS buffers against previous range's readers
        const int qr0 = qt * 64 + wid * 16;
        half8 aq0 = *reinterpret_cast<const half8*>(qh + (size_t)(qr0 + lr) * HD + lg * 8);
        half8 aq1 = *reinterpret_cast<const half8*>(qh + (size_t)(qr0 + lr) * HD + 32 + lg * 8);
#pragma unroll
        for (int e = 0; e < 8; e++) {  // fold 1/8 score scale into Q (exact: pow2)
            aq0[e] *= (fp16)0.125f;
            aq1[e] *= (fp16)0.125f;
        }
        f32x4 o[4] = {};
        float m[4], lsum[4];
#pragma unroll
        for (int r = 0; r < 4; r++) { m[r] = -1e30f; lsum[r] = 0.0f; }

        if (t_lo < t_hi) {
            stage(t_lo, 0);
            __syncthreads();
            for (int tt = t_lo; tt < t_hi; ++tt) {
                const int cur = (tt - t_lo) & 1;
                if (tt + 1 < t_hi) stage(tt + 1, cur ^ 1);
                const int kv0 = tt << 6;
                f32x4 sc[4];
                __builtin_amdgcn_s_setprio(1);
#pragma unroll
                for (int f = 0; f < 4; ++f) {
                    int row = f * 16 + lr;
                    const char* kbp = (const char*)&Kb[cur][row][0];
                    half8 b0 = *(const half8*)(kbp + (((lg) ^ (row & 7)) * 16));
                    half8 b1 = *(const half8*)(kbp + (((4 + lg) ^ (row & 7)) * 16));
                    f32x4 s = {};
                    s = __builtin_amdgcn_mfma_f32_16x16x32_f16(aq0, b0, s, 0, 0, 0);
                    s = __builtin_amdgcn_mfma_f32_16x16x32_f16(aq1, b1, s, 0, 0, 0);
                    sc[f] = s;
                }
                __builtin_amdgcn_s_setprio(0);
                if (tt == qt) {
#pragma unroll
                    for (int f = 0; f < 4; f++)
#pragma unroll
                        for (int r = 0; r < 4; r++) {
                            int q = qr0 + lg * 4 + r, kv = kv0 + f * 16 + lr;
                            if (kv > q) sc[f][r] = -1e30f;
                        }
                }
                // defer-max
                float lmax[4];
                bool ok = true;
#pragma unroll
                for (int r = 0; r < 4; r++) {
                    lmax[r] = fmaxf(fmaxf(sc[0][r], sc[1][r]), fmaxf(sc[2][r], sc[3][r]));
                    ok = ok && (lmax[r] <= m[r] + 8.0f);
                }
                if (!__all(ok)) {
#pragma unroll
                    for (int r = 0; r < 4; r++) {
                        float v = lmax[r];
                        v = fmaxf(v, __shfl_xor(v, 1));
                        v = fmaxf(v, __shfl_xor(v, 2));
                        v = fmaxf(v, __shfl_xor(v, 4));
                        v = fmaxf(v, __shfl_xor(v, 8));
                        float mn = fmaxf(m[r], v);
                        float alpha = __expf(m[r] - mn);
                        m[r] = mn;
                        lsum[r] *= alpha;
#pragma unroll
                        for (int vf = 0; vf < 4; vf++) o[vf][r] *= alpha;
                    }
                }
#pragma unroll
                for (int f = 0; f < 4; f++)
#pragma unroll
                    for (int r = 0; r < 4; r++) {
                        float pp = __expf(sc[f][r] - m[r]);  // bounded by e^8
                        sc[f][r] = pp;
                        lsum[r] += pp;
                    }
                // P write: stride-64 rows, 16B-chunk XOR swizzle (chunk ^= row&7)
                {
                    char* pb = (char*)&P[wid][0][0];
#pragma unroll
                    for (int f = 0; f < 4; f++)
#pragma unroll
                        for (int r = 0; r < 4; r++) {
                            int row = lg * 4 + r, col = f * 16 + lr;
                            *(fp16*)(pb + row * 128 + (((col >> 3) ^ (row & 7)) * 16) + (col & 7) * 2) =
                                (fp16)sc[f][r];
                        }
                }
                __builtin_amdgcn_s_setprio(1);
#pragma unroll
                for (int half = 0; half < 2; half++) {
                    const char* pb = (const char*)&P[wid][0][0];
                    half8 pa = *(const half8*)(pb + lr * 128 + (((half * 4 + lg) ^ (lr & 7)) * 16));
#pragma unroll
                    for (int vf = 0; vf < 4; vf++) {
                        int d = vf * 16 + lr;
                        int xo = ((half * 4 + lg) ^ (d & 7)) * 16;
                        half8 bv = *(const half8*)((const char*)&Vb[cur][d][0] + xo);
                        o[vf] = __builtin_amdgcn_mfma_f32_16x16x32_f16(pa, bv, o[vf], 0, 0, 0);
                    }
                }
                __builtin_amdgcn_s_setprio(0);
                __syncthreads();
            }
        }
        // final row-sum reduce
#pragma unroll
        for (int r = 0; r < 4; r++) {
            float v = lsum[r];
            v += __shfl_xor(v, 1);
            v += __shfl_xor(v, 2);
            v += __shfl_xor(v, 4);
            v += __shfl_xor(v, 8);
            lsum[r] = v;
        }
        if (mode == 0) {
#pragma unroll
            for (int vf = 0; vf < 4; vf++)
#pragma unroll
                for (int r = 0; r < 4; r++) {
                    float v = o[vf][r] / lsum[r];
                    o_all[(size_t)(qr0 + lg * 4 + r) * 2048 + head * 64 + vf * 16 + lr] = (fp16)v;
                }
        } else {
            float inv[4];
#pragma unroll
            for (int r = 0; r < 4; r++) inv[r] = (lsum[r] > 0.0f) ? 1.0f / lsum[r] : 0.0f;
            const size_t sb = ((size_t)(p * 32 + head) * 2 + slot);
            fp16* po = part_o + sb * 4096;
            float* pm = part_mlog + sb * 64;
#pragma unroll
            for (int vf = 0; vf < 4; vf++)
#pragma unroll
                for (int r = 0; r < 4; r++) {
                    int rl = wid * 16 + lg * 4 + r;
                    po[rl * 64 + vf * 16 + lr] = (fp16)(o[vf][r] * inv[r]);
                }
            if (lr == 0) {
#pragma unroll
                for (int r = 0; r < 4; r++) {
                    int rl = wid * 16 + lg * 4 + r;
                    pm[rl] = (lsum[r] > 0.0f) ? m[r] + __logf(lsum[r]) : -1e30f;
                }
            }
        }
    };

    if (halfB == 0) {
        run_range(p, 0, p + 1, 0, 0);           // light tile: full causal, direct write
        run_range(31 - p, 0, 15 - p, 1, 0);     // heavy tile prefix (may be empty at p=15)
    } else {
        run_range(31 - p, 15 - p, 32 - p, 1, 1); // heavy tile suffix incl diagonal
    }
}

// ---------------- combine: merge 2 LSE partials per (pair, head) into o_all heavy rows ----------------
__global__ void attn_combine(const fp16* __restrict__ part_o, const float* __restrict__ part_mlog,
                             fp16* __restrict__ o_all) {
    const int bx = blockIdx.x;           // 512 = 16 pairs * 32 heads
    const int head = bx & 31, p = bx >> 5;
    const int qt2 = 31 - p;
    const int t = threadIdx.x;
    const int row = t >> 2, c0 = (t & 3) * 16;
    const size_t base = (size_t)(p * 32 + head) * 2;
    const float m0 = part_mlog[(base + 0) * 64 + row];
    const float m1 = part_mlog[(base + 1) * 64 + row];
    const float M = fmaxf(m0, m1);
    const float w0 = __expf(m0 - M), w1 = __expf(m1 - M);
    const float inv = 1.0f / (w0 + w1);
    const fp16* p0 = part_o + (base + 0) * 4096 + row * 64 + c0;
    const fp16* p1 = part_o + (base + 1) * 4096 + row * 64 + c0;
    fp16* dst = o_all + (size_t)(qt2 * 64 + row) * 2048 + head * 64 + c0;
    half8 a0 = *(const half8*)p0, a1 = *(const half8*)(p0 + 8);
    half8 b0 = *(const half8*)p1, b1 = *(const half8*)(p1 + 8);
    half8 r0, r1;
#pragma unroll
    for (int j = 0; j < 8; j++) {
        r0[j] = (fp16)((w0 * (float)a0[j] + w1 * (float)b0[j]) * inv);
        r1[j] = (fp16)((w0 * (float)a1[j] + w1 * (float)b1[j]) * inv);
    }
    *(half8*)dst = r0;
    *(half8*)(dst + 8) = r1;
}

extern "C" void kernel_launch(void* const* d_in, const int* in_sizes, int n_in,
                              void* d_out, int out_size, void* d_ws, size_t ws_size,
                              hipStream_t stream) {
    const float* x  = (const float*)d_in[0];
    const float* wq = (const float*)d_in[1];
    const float* wk = (const float*)d_in[2];
    const float* wv = (const float*)d_in[3];
    const float* wo = (const float*)d_in[4];
    float* out = (float*)d_out;
    char* ws = (char*)d_ws;

    // Workspace (44 MB peak). Aliases: w2t reuses xh (dead after gemm_proj);
    // o_all reuses proj (dead after rope_vt); partials reuse wqkvt (dead after gemm_proj).
    fp16*  xh        = (fp16*)(ws);                       // 8 MB [2048][2048]
    fp16*  w2t       = xh;                                // alias
    fp16*  wqkvt     = (fp16*)(ws + ((size_t)8 << 20));   // 12 MB [3072][2048]
    fp16*  part_o    = (fp16*)(ws + ((size_t)8 << 20));   // alias: 8 MB [16][32][2][64][64]
    float* part_mlog = (float*)(ws + ((size_t)16 << 20)); // alias: 256 KB [16][32][2][64]
    fp16*  proj      = (fp16*)(ws + ((size_t)20 << 20));  // 12 MB [2048][3072]
    fp16*  o_all     = proj;                              // alias (8 MB)
    fp16*  qbuf      = (fp16*)(ws + ((size_t)32 << 20));  // 8 MB [32][2048][64]
    fp16*  kbuf      = (fp16*)(ws + ((size_t)40 << 20));  // 2 MB [8][2048][64]
    fp16*  vtb       = (fp16*)(ws + ((size_t)42 << 20));  // 2 MB [8][64][2048]

    cast_f32_f16<<<dim3(4096), 256, 0, stream>>>(x, xh, SEQ * DIMM);
    transpose_qkvw<<<dim3(32, 1, 48), 256, 0, stream>>>(wq, wk, wv, wqkvt);
    gemm_proj<<<dim3(16, 24), 256, 0, stream>>>(xh, wqkvt, proj);
    rope_vt_kernel<<<dim3(10496), 256, 0, stream>>>(proj, qbuf, kbuf, vtb);
    transpose_cast<<<dim3(32, 32), 256, 0, stream>>>(wo, w2t, 2048, 2048);
    attn_kernel<<<dim3(1024), 256, 0, stream>>>(qbuf, kbuf, vtb, o_all, part_o, part_mlog);
    attn_combine<<<dim3(512), 256, 0, stream>>>(part_o, part_mlog, o_all);
    gemm_out2<<<dim3(16, 16), 256, 0, stream>>>(o_all, w2t, out);
}

// Round 14
// 143.980 us; speedup vs baseline: 1.1700x; 1.1700x over previous
//
#include <hip/hip_runtime.h>
#include <hip/hip_bf16.h>

#define SEQ 2048
#define DIMM 2048
#define NQH 32
#define NKVH 8
#define HD 64

typedef _Float16 half8 __attribute__((ext_vector_type(8)));
typedef float f32x4 __attribute__((ext_vector_type(4)));
using fp16 = _Float16;

typedef __attribute__((address_space(1))) unsigned int ga_u32;
typedef __attribute__((address_space(3))) unsigned int ls_u32;

__device__ __forceinline__ void gll16(const void* g, void* l) {
    __builtin_amdgcn_global_load_lds((const ga_u32*)g, (ls_u32*)l, 16, 0, 0);
}

// ---------------- cast fp32 -> fp16 (vectorized) ----------------
__global__ void cast_f32_f16(const float* __restrict__ in, fp16* __restrict__ out, int n) {
    int i = (blockIdx.x * 256 + threadIdx.x) * 4;
    if (i < n) {
        float4 v = *reinterpret_cast<const float4*>(in + i);
#pragma unroll
        for (int j = 0; j < 4; j++) out[i + j] = (fp16)(&v.x)[j];
    }
}

// ------------- fused weight transpose: wq/wk/wv fp32 [head][2048][64] -> wqkvt fp16 [48][64][2048] -------------
__global__ void transpose_qkvw(const float* __restrict__ wq, const float* __restrict__ wk,
                               const float* __restrict__ wv, fp16* __restrict__ out) {
    __shared__ float tile[64][65];
    const int z = blockIdx.z;
    const float* inh = (z < 32) ? wq + (size_t)z * SEQ * HD
                                : (z < 40) ? wk + (size_t)(z - 32) * SEQ * HD
                                           : wv + (size_t)(z - 40) * SEQ * HD;
    fp16* outh = out + (size_t)z * HD * SEQ;
    int r0 = blockIdx.x * 64;
    int t = threadIdx.x;
#pragma unroll
    for (int i = 0; i < 16; i++) {
        int idx = i * 256 + t;
        int r = idx >> 6, c = idx & 63;
        tile[r][c] = inh[(size_t)(r0 + r) * HD + c];
    }
    __syncthreads();
#pragma unroll
    for (int i = 0; i < 16; i++) {
        int idx = i * 256 + t;
        int cc = idx >> 6, rr = idx & 63;
        outh[(size_t)cc * SEQ + r0 + rr] = (fp16)tile[rr][cc];
    }
}

// ------------- tiled transpose + cast: in fp32 [R][C] -> out fp16 [C][R] (for w_out) -------------
__global__ void transpose_cast(const float* __restrict__ in, fp16* __restrict__ out, int R, int C) {
    __shared__ float tile[64][65];
    int r0 = blockIdx.x * 64, c0 = blockIdx.y * 64;
    int t = threadIdx.x;
#pragma unroll
    for (int i = 0; i < 16; i++) {
        int idx = i * 256 + t;
        int r = idx >> 6, c = idx & 63;
        tile[r][c] = in[(size_t)(r0 + r) * C + c0 + c];
    }
    __syncthreads();
#pragma unroll
    for (int i = 0; i < 16; i++) {
        int idx = i * 256 + t;
        int cc = idx >> 6, rr = idx & 63;
        out[(size_t)(c0 + cc) * R + r0 + rr] = (fp16)tile[rr][cc];
    }
}

// ---------------- fused RoPE + V-transpose (both read proj[2048][3072]) ----------------
__global__ void rope_vt_kernel(const fp16* __restrict__ proj, fp16* __restrict__ qb,
                               fp16* __restrict__ kb, fp16* __restrict__ vtb) {
    __shared__ fp16 tile[64][72];
    const int bx = blockIdx.x;
    if (bx < 10240) {
        int tid = bx * 256 + threadIdx.x;  // 40*2048*32
        int pair = tid & 31;
        int s = (tid >> 5) & 2047;
        int head = tid >> 16;
        const fp16* src = proj + (size_t)s * 3072 + head * HD + 2 * pair;
        float x1 = (float)src[0];
        float x2 = (float)src[1];
        float invf = expf(-((float)pair / 32.0f) * 9.210340371976184f);  // 10000^(-2j/64)
        float ang = (float)s * invf;
        float sn, cs;
        sincosf(ang, &sn, &cs);
        float o1 = cs * x1 - sn * x2;
        float o2 = sn * x1 + cs * x2;
        fp16* dst = (head < NQH) ? (qb + ((size_t)head * SEQ + s) * HD + 2 * pair)
                                 : (kb + ((size_t)(head - NQH) * SEQ + s) * HD + 2 * pair);
        dst[0] = (fp16)o1;
        dst[1] = (fp16)o2;
    } else {
        const int idx = bx - 10240;          // 0..255
        const int g = idx >> 5;              // kv group
        const int s0 = (idx & 31) * 64;      // seq tile
        const int t = threadIdx.x;
#pragma unroll
        for (int i = 0; i < 16; i++) {
            int id2 = i * 256 + t;
            int r = id2 >> 6, c = id2 & 63;
            tile[r][c] = proj[(size_t)(s0 + r) * 3072 + 2560 + g * HD + c];
        }
        __syncthreads();
#pragma unroll
        for (int i = 0; i < 16; i++) {
            int id2 = i * 256 + t;
            int cc = id2 >> 6, rr = id2 & 63;
            vtb[((size_t)g * HD + cc) * SEQ + s0 + rr] = tile[rr][cc];
        }
    }
}

// ============ Templated GEMM core: BMxBN tile, BK=64, double-buffered gll staging, XOR swizzle ===
// 4 waves (2x2), wave tile (BM/2)x(BN/2); MR=BM/32, NR=BN/32 frags of 16x16.
// BM=64, BN=128 -> LDS 48 KB -> 3 blocks/CU capacity.
template <int BM, int BN, int WF32>
__global__ __launch_bounds__(256) void gemm_tpl(
    const fp16* __restrict__ A, const fp16* __restrict__ Bt, void* __restrict__ Cout, int Nout) {
    __shared__ fp16 As[2][BM][64];
    __shared__ fp16 Bs[2][BN][64];
    const int t = threadIdx.x;
    const int m0 = blockIdx.x * BM, n0 = blockIdx.y * BN;
    const int wid = t >> 6, lane = t & 63;
    const int wm = (wid >> 1) * (BM / 2), wn = (wid & 1) * (BN / 2);
    const int lr = lane & 15, lg = lane >> 4;
    constexpr int MR = BM / 32, NR = BN / 32;
    f32x4 acc[MR][NR] = {};
    auto stage_ = [&](int kt, int b) {
#pragma unroll
        for (int s = t; s < BM * 8; s += 256) {
            int row = s >> 3, ch = s & 7;
            int lch = ch ^ (row & 7);  // pre-swizzled global source, linear LDS dest
            gll16(A + (size_t)(m0 + row) * 2048 + (kt << 6) + lch * 8,
                  (char*)&As[b][0][0] + s * 16);
        }
#pragma unroll
        for (int s = t; s < BN * 8; s += 256) {
            int row = s >> 3, ch = s & 7;
            int lch = ch ^ (row & 7);
            gll16(Bt + (size_t)(n0 + row) * 2048 + (kt << 6) + lch * 8,
                  (char*)&Bs[b][0][0] + s * 16);
        }
    };
    stage_(0, 0);
    __syncthreads();
    for (int kt = 0; kt < 32; ++kt) {
        const int cur = kt & 1;
        if (kt + 1 < 32) stage_(kt + 1, cur ^ 1);
#pragma unroll
        for (int kk = 0; kk < 2; kk++) {
            half8 af[MR], bfv[NR];
#pragma unroll
            for (int m = 0; m < MR; m++) {
                int row = wm + m * 16 + lr;
                af[m] = *(const half8*)((const char*)&As[cur][row][0] +
                                        (((kk * 4 + lg) ^ (row & 7)) * 16));
            }
#pragma unroll
            for (int n = 0; n < NR; n++) {
                int row = wn + n * 16 + lr;
                bfv[n] = *(const half8*)((const char*)&Bs[cur][row][0] +
                                         (((kk * 4 + lg) ^ (row & 7)) * 16));
            }
            __builtin_amdgcn_s_setprio(1);
#pragma unroll
            for (int m = 0; m < MR; m++)
#pragma unroll
                for (int n = 0; n < NR; n++)
                    acc[m][n] = __builtin_amdgcn_mfma_f32_16x16x32_f16(af[m], bfv[n], acc[m][n], 0, 0, 0);
            __builtin_amdgcn_s_setprio(0);
        }
        __syncthreads();  // vmcnt drained here -> next tile ready; protects buf reuse
    }
#pragma unroll
    for (int m = 0; m < MR; m++)
#pragma unroll
        for (int n = 0; n < NR; n++)
#pragma unroll
            for (int r = 0; r < 4; r++) {
                int row = m0 + wm + m * 16 + lg * 4 + r;
                int col = n0 + wn + n * 16 + lr;
                if (WF32)
                    ((float*)Cout)[(size_t)row * Nout + col] = acc[m][n][r];
                else
                    ((fp16*)Cout)[(size_t)row * Nout + col] = (fp16)acc[m][n][r];
            }
}

// ---------------- causal flash attention (round-12 body: 40960B LDS, balanced bijective qt map) ----
// grid (1024): head = bx & 31; grp = bx>>5; a = grp&7, sel = grp>>3:
//   qt = {31-a, 8+a, 23-a, a}[sel]  — bijective over 0..31 (verified passing, round 12).
__global__ __launch_bounds__(256) void attn_kernel(
    const fp16* __restrict__ qb, const fp16* __restrict__ kb,
    const fp16* __restrict__ vt, fp16* __restrict__ o_all) {
    __shared__ fp16 Kb[2][64][64];  // 16 KB (16B-chunk XOR swizzled)
    __shared__ fp16 Vb[2][64][64];  // 16 KB (swizzled)
    __shared__ fp16 P[4][16][64];   //  8 KB (swizzled stride-64) -> 40960 B total
    const int t = threadIdx.x, wid = t >> 6, lane = t & 63;
    const int bx = blockIdx.x;
    const int grp = bx >> 5;  // 0..31
    const int a = grp & 7;
    const int sel = grp >> 3;
    const int qt = (sel == 0) ? (31 - a) : (sel == 1) ? (8 + a) : (sel == 2) ? (23 - a) : a;
    const int head = bx & 31;
    const int g = head >> 2;
    const int lr = lane & 15, lg = lane >> 4;
    const fp16* qh = qb + (size_t)head * SEQ * HD;
    const fp16* kh = kb + (size_t)g * SEQ * HD;
    const fp16* vh = vt + (size_t)g * HD * SEQ;
    const int srow = lane >> 3, schunk = lane & 7;
    const int qr0 = qt * 64 + wid * 16;

    half8 aq0 = *reinterpret_cast<const half8*>(qh + (size_t)(qr0 + lr) * HD + lg * 8);
    half8 aq1 = *reinterpret_cast<const half8*>(qh + (size_t)(qr0 + lr) * HD + 32 + lg * 8);
#pragma unroll
    for (int e = 0; e < 8; e++) {  // fold 1/8 score scale into Q (exact: pow2)
        aq0[e] *= (fp16)0.125f;
        aq1[e] *= (fp16)0.125f;
    }
    f32x4 o[4] = {};
    float m[4], lsum[4];  // lsum lane-partial until the end
#pragma unroll
    for (int r = 0; r < 4; r++) { m[r] = -1e30f; lsum[r] = 0.0f; }
    const int nt = qt + 1;

    auto stage = [&](int kt, int b) {
        const int kv0 = kt << 6;
#pragma unroll
        for (int i = 0; i < 2; ++i) {
            int row = wid * 16 + i * 8 + srow;
            int sw = (schunk ^ srow) * 8;
            gll16(kh + (size_t)(kv0 + row) * HD + sw, &Kb[b][wid * 16 + i * 8][0]);
            gll16(vh + (size_t)row * SEQ + kv0 + sw, &Vb[b][wid * 16 + i * 8][0]);
        }
    };

    stage(0, 0);
    __syncthreads();
    for (int tt = 0; tt < nt; ++tt) {
        const int cur = tt & 1;
        if (tt + 1 < nt) stage(tt + 1, cur ^ 1);
        const int kv0 = tt << 6;
        f32x4 sc[4];
        __builtin_amdgcn_s_setprio(1);
#pragma unroll
        for (int f = 0; f < 4; ++f) {
            int row = f * 16 + lr;
            const char* kbp = (const char*)&Kb[cur][row][0];
            half8 b0 = *(const half8*)(kbp + (((lg) ^ (row & 7)) * 16));
            half8 b1 = *(const half8*)(kbp + (((4 + lg) ^ (row & 7)) * 16));
            f32x4 s = {};
            s = __builtin_amdgcn_mfma_f32_16x16x32_f16(aq0, b0, s, 0, 0, 0);
            s = __builtin_amdgcn_mfma_f32_16x16x32_f16(aq1, b1, s, 0, 0, 0);
            sc[f] = s;
        }
        __builtin_amdgcn_s_setprio(0);
        if (tt == qt) {
#pragma unroll
            for (int f = 0; f < 4; f++)
#pragma unroll
                for (int r = 0; r < 4; r++) {
                    int q = qr0 + lg * 4 + r, kv = kv0 + f * 16 + lr;
                    if (kv > q) sc[f][r] = -1e30f;
                }
        }
        // ---- defer-max: lane-local check; rescale only if some row grew past m+8 ----
        float lmax[4];
        bool ok = true;
#pragma unroll
        for (int r = 0; r < 4; r++) {
            lmax[r] = fmaxf(fmaxf(sc[0][r], sc[1][r]), fmaxf(sc[2][r], sc[3][r]));
            ok = ok && (lmax[r] <= m[r] + 8.0f);
        }
        if (!__all(ok)) {  // rare path: full cross-lane max + rescale
#pragma unroll
            for (int r = 0; r < 4; r++) {
                float v = lmax[r];
                v = fmaxf(v, __shfl_xor(v, 1));
                v = fmaxf(v, __shfl_xor(v, 2));
                v = fmaxf(v, __shfl_xor(v, 4));
                v = fmaxf(v, __shfl_xor(v, 8));
                float mn = fmaxf(m[r], v);
                float alpha = __expf(m[r] - mn);
                m[r] = mn;
                lsum[r] *= alpha;
#pragma unroll
                for (int vf = 0; vf < 4; vf++) o[vf][r] *= alpha;
            }
        }
#pragma unroll
        for (int f = 0; f < 4; f++)
#pragma unroll
            for (int r = 0; r < 4; r++) {
                float p = __expf(sc[f][r] - m[r]);  // bounded by e^8
                sc[f][r] = p;
                lsum[r] += p;  // lane-partial; reduced once at the end
            }
        // P write: stride-64 rows, 16B-chunk XOR swizzle (chunk ^= row&7)
        {
            char* pb = (char*)&P[wid][0][0];
#pragma unroll
            for (int f = 0; f < 4; f++)
#pragma unroll
                for (int r = 0; r < 4; r++) {
                    int row = lg * 4 + r, col = f * 16 + lr;
                    *(fp16*)(pb + row * 128 + (((col >> 3) ^ (row & 7)) * 16) + (col & 7) * 2) =
                        (fp16)sc[f][r];
                }
        }
        __builtin_amdgcn_s_setprio(1);
#pragma unroll
        for (int half = 0; half < 2; half++) {
            const char* pb = (const char*)&P[wid][0][0];
            half8 pa = *(const half8*)(pb + lr * 128 + (((half * 4 + lg) ^ (lr & 7)) * 16));
#pragma unroll
            for (int vf = 0; vf < 4; vf++) {
                int d = vf * 16 + lr;
                int xo = ((half * 4 + lg) ^ (d & 7)) * 16;
                half8 bv = *(const half8*)((const char*)&Vb[cur][d][0] + xo);
                o[vf] = __builtin_amdgcn_mfma_f32_16x16x32_f16(pa, bv, o[vf], 0, 0, 0);
            }
        }
        __builtin_amdgcn_s_setprio(0);
        __syncthreads();  // drains vmcnt (stage of tt+1) + protects buffer reuse
    }
    // final row-sum reduce (once)
#pragma unroll
    for (int r = 0; r < 4; r++) {
        float v = lsum[r];
        v += __shfl_xor(v, 1);
        v += __shfl_xor(v, 2);
        v += __shfl_xor(v, 4);
        v += __shfl_xor(v, 8);
        lsum[r] = v;
    }
#pragma unroll
    for (int vf = 0; vf < 4; vf++)
#pragma unroll
        for (int r = 0; r < 4; r++) {
            float v = o[vf][r] / lsum[r];
            o_all[(size_t)(qr0 + lg * 4 + r) * 2048 + head * 64 + vf * 16 + lr] = (fp16)v;
        }
}

extern "C" void kernel_launch(void* const* d_in, const int* in_sizes, int n_in,
                              void* d_out, int out_size, void* d_ws, size_t ws_size,
                              hipStream_t stream) {
    const float* x  = (const float*)d_in[0];
    const float* wq = (const float*)d_in[1];
    const float* wk = (const float*)d_in[2];
    const float* wv = (const float*)d_in[3];
    const float* wo = (const float*)d_in[4];
    float* out = (float*)d_out;
    char* ws = (char*)d_ws;

    // Workspace (44 MB peak). Aliases: w2t reuses xh (dead after gemm_proj);
    // o_all reuses proj (dead after rope_vt).
    fp16* xh    = (fp16*)(ws);                        // 8 MB [2048][2048]
    fp16* w2t   = xh;                                 // alias
    fp16* wqkvt = (fp16*)(ws + ((size_t)8 << 20));    // 12 MB [3072][2048] ([48][64][2048])
    fp16* proj  = (fp16*)(ws + ((size_t)20 << 20));   // 12 MB [2048][3072]
    fp16* o_all = proj;                               // alias (8 MB)
    fp16* qbuf  = (fp16*)(ws + ((size_t)32 << 20));   // 8 MB [32][2048][64]
    fp16* kbuf  = (fp16*)(ws + ((size_t)40 << 20));   // 2 MB [8][2048][64]
    fp16* vtb   = (fp16*)(ws + ((size_t)42 << 20));   // 2 MB [8][64][2048]

    cast_f32_f16<<<dim3(4096), 256, 0, stream>>>(x, xh, SEQ * DIMM);
    transpose_qkvw<<<dim3(32, 1, 48), 256, 0, stream>>>(wq, wk, wv, wqkvt);
    // proj: M=2048 (BM=64 -> 32), N=3072 (BN=128 -> 24) => 768 blocks = uniform 3/CU
    gemm_tpl<64, 128, 0><<<dim3(32, 24), 256, 0, stream>>>(xh, wqkvt, proj, 3072);
    rope_vt_kernel<<<dim3(10496), 256, 0, stream>>>(proj, qbuf, kbuf, vtb);
    transpose_cast<<<dim3(32, 32), 256, 0, stream>>>(wo, w2t, 2048, 2048);
    attn_kernel<<<dim3(1024), 256, 0, stream>>>(qbuf, kbuf, vtb, o_all);
    // out: M=2048 (32), N=2048 (16) => 512 blocks = uniform 2/CU, fp32 output
    gemm_tpl<64, 128, 1><<<dim3(32, 16), 256, 0, stream>>>(o_all, w2t, out, 2048);
}

// Round 16
// 133.769 us; speedup vs baseline: 1.2593x; 1.0763x over previous
//
#include <hip/hip_runtime.h>
#include <hip/hip_bf16.h>

#define SEQ 2048
#define DIMM 2048
#define NQH 32
#define NKVH 8
#define HD 64

typedef _Float16 half8 __attribute__((ext_vector_type(8)));
typedef float f32x4 __attribute__((ext_vector_type(4)));
typedef __fp16 fp16raw2 __attribute__((ext_vector_type(2)));
using fp16 = _Float16;

typedef __attribute__((address_space(1))) unsigned int ga_u32;
typedef __attribute__((address_space(3))) unsigned int ls_u32;

__device__ __forceinline__ void gll16(const void* g, void* l) {
    __builtin_amdgcn_global_load_lds((const ga_u32*)g, (ls_u32*)l, 16, 0, 0);
}

// ============ merged prep: cast x -> fp16, transpose wq/wk/wv, transpose w_out ============
// blocks [0,1024): cast; [1024,2560): wqkv transpose; [2560,3584): w_out transpose.
__global__ void prep_kernel(const float* __restrict__ x,
                            const float* __restrict__ wq, const float* __restrict__ wk,
                            const float* __restrict__ wv, const float* __restrict__ wo,
                            fp16* __restrict__ xh, fp16* __restrict__ wqkvt,
                            fp16* __restrict__ w2t) {
    __shared__ float tile[64][65];
    const int bx = blockIdx.x;
    const int t = threadIdx.x;
    if (bx < 1024) {
#pragma unroll
        for (int it = 0; it < 4; it++) {
            int i = bx * 4096 + it * 1024 + t * 4;
            float4 v = *reinterpret_cast<const float4*>(x + i);
            fp16* o = xh + i;
            o[0] = (fp16)v.x; o[1] = (fp16)v.y; o[2] = (fp16)v.z; o[3] = (fp16)v.w;
        }
    } else if (bx < 2560) {
        const int zi = bx - 1024;
        const int z = zi >> 5;
        const int r0 = (zi & 31) * 64;
        const float* inh = (z < 32) ? wq + (size_t)z * SEQ * HD
                                    : (z < 40) ? wk + (size_t)(z - 32) * SEQ * HD
                                               : wv + (size_t)(z - 40) * SEQ * HD;
        fp16* outh = wqkvt + (size_t)z * HD * SEQ;
#pragma unroll
        for (int i = 0; i < 16; i++) {
            int idx = i * 256 + t;
            int r = idx >> 6, c = idx & 63;
            tile[r][c] = inh[(size_t)(r0 + r) * HD + c];
        }
        __syncthreads();
#pragma unroll
        for (int i = 0; i < 16; i++) {
            int idx = i * 256 + t;
            int cc = idx >> 6, rr = idx & 63;
            outh[(size_t)cc * SEQ + r0 + rr] = (fp16)tile[rr][cc];
        }
    } else {
        const int zi = bx - 2560;
        const int r0 = (zi >> 5) * 64, c0 = (zi & 31) * 64;
#pragma unroll
        for (int i = 0; i < 16; i++) {
            int idx = i * 256 + t;
            int r = idx >> 6, c = idx & 63;
            tile[r][c] = wo[(size_t)(r0 + r) * 2048 + c0 + c];
        }
        __syncthreads();
#pragma unroll
        for (int i = 0; i < 16; i++) {
            int idx = i * 256 + t;
            int cc = idx >> 6, rr = idx & 63;
            w2t[(size_t)(c0 + cc) * 2048 + r0 + rr] = (fp16)tile[rr][cc];
        }
    }
}

// ---------------- fused RoPE + V-transpose; q gets 0.125*log2(e) scale folded in ----------------
__global__ void rope_vt_kernel(const fp16* __restrict__ proj, fp16* __restrict__ qb,
                               fp16* __restrict__ kb, fp16* __restrict__ vtb) {
    __shared__ fp16 tile[64][72];
    const int bx = blockIdx.x;
    if (bx < 10240) {
        int tid = bx * 256 + threadIdx.x;  // 40*2048*32
        int pair = tid & 31;
        int s = (tid >> 5) & 2047;
        int head = tid >> 16;
        const fp16* src = proj + (size_t)s * 3072 + head * HD + 2 * pair;
        float x1 = (float)src[0];
        float x2 = (float)src[1];
        float invf = expf(-((float)pair / 32.0f) * 9.210340371976184f);  // 10000^(-2j/64)
        float ang = (float)s * invf;
        float sn, cs;
        sincosf(ang, &sn, &cs);
        float o1 = cs * x1 - sn * x2;
        float o2 = sn * x1 + cs * x2;
        fp16* dst;
        if (head < NQH) {
            o1 *= 0.18033688011112042f;  // 0.125 * log2(e): scores in log2 units
            o2 *= 0.18033688011112042f;
            dst = qb + ((size_t)head * SEQ + s) * HD + 2 * pair;
        } else {
            dst = kb + ((size_t)(head - NQH) * SEQ + s) * HD + 2 * pair;
        }
        dst[0] = (fp16)o1;
        dst[1] = (fp16)o2;
    } else {
        const int idx = bx - 10240;          // 0..255
        const int g = idx >> 5;              // kv group
        const int s0 = (idx & 31) * 64;      // seq tile
        const int t = threadIdx.x;
#pragma unroll
        for (int i = 0; i < 16; i++) {
            int id2 = i * 256 + t;
            int r = id2 >> 6, c = id2 & 63;
            tile[r][c] = proj[(size_t)(s0 + r) * 3072 + 2560 + g * HD + c];
        }
        __syncthreads();
#pragma unroll
        for (int i = 0; i < 16; i++) {
            int id2 = i * 256 + t;
            int cc = id2 >> 6, rr = id2 & 63;
            vtb[((size_t)g * HD + cc) * SEQ + s0 + rr] = tile[rr][cc];
        }
    }
}

// ============ Templated GEMM core: BMxBN tile, BK=64, double-buffered gll staging, XOR swizzle ===
template <int BM, int BN, int WF32>
__global__ __launch_bounds__(256) void gemm_tpl(
    const fp16* __restrict__ A, const fp16* __restrict__ Bt, void* __restrict__ Cout, int Nout) {
    __shared__ fp16 As[2][BM][64];
    __shared__ fp16 Bs[2][BN][64];
    const int t = threadIdx.x;
    const int m0 = blockIdx.x * BM, n0 = blockIdx.y * BN;
    const int wid = t >> 6, lane = t & 63;
    const int wm = (wid >> 1) * (BM / 2), wn = (wid & 1) * (BN / 2);
    const int lr = lane & 15, lg = lane >> 4;
    constexpr int MR = BM / 32, NR = BN / 32;
    f32x4 acc[MR][NR] = {};
    auto stage_ = [&](int kt, int b) {
#pragma unroll
        for (int s = t; s < BM * 8; s += 256) {
            int row = s >> 3, ch = s & 7;
            int lch = ch ^ (row & 7);  // pre-swizzled global source, linear LDS dest
            gll16(A + (size_t)(m0 + row) * 2048 + (kt << 6) + lch * 8,
                  (char*)&As[b][0][0] + s * 16);
        }
#pragma unroll
        for (int s = t; s < BN * 8; s += 256) {
            int row = s >> 3, ch = s & 7;
            int lch = ch ^ (row & 7);
            gll16(Bt + (size_t)(n0 + row) * 2048 + (kt << 6) + lch * 8,
                  (char*)&Bs[b][0][0] + s * 16);
        }
    };
    stage_(0, 0);
    __syncthreads();
    for (int kt = 0; kt < 32; ++kt) {
        const int cur = kt & 1;
        if (kt + 1 < 32) stage_(kt + 1, cur ^ 1);
#pragma unroll
        for (int kk = 0; kk < 2; kk++) {
            half8 af[MR], bfv[NR];
#pragma unroll
            for (int m = 0; m < MR; m++) {
                int row = wm + m * 16 + lr;
                af[m] = *(const half8*)((const char*)&As[cur][row][0] +
                                        (((kk * 4 + lg) ^ (row & 7)) * 16));
            }
#pragma unroll
            for (int n = 0; n < NR; n++) {
                int row = wn + n * 16 + lr;
                bfv[n] = *(const half8*)((const char*)&Bs[cur][row][0] +
                                         (((kk * 4 + lg) ^ (row & 7)) * 16));
            }
            __builtin_amdgcn_s_setprio(1);
#pragma unroll
            for (int m = 0; m < MR; m++)
#pragma unroll
                for (int n = 0; n < NR; n++)
                    acc[m][n] = __builtin_amdgcn_mfma_f32_16x16x32_f16(af[m], bfv[n], acc[m][n], 0, 0, 0);
            __builtin_amdgcn_s_setprio(0);
        }
        __syncthreads();  // vmcnt drained here -> next tile ready; protects buf reuse
    }
#pragma unroll
    for (int m = 0; m < MR; m++)
#pragma unroll
        for (int n = 0; n < NR; n++)
#pragma unroll
            for (int r = 0; r < 4; r++) {
                int row = m0 + wm + m * 16 + lg * 4 + r;
                int col = n0 + wn + n * 16 + lr;
                if (WF32)
                    ((float*)Cout)[(size_t)row * Nout + col] = acc[m][n][r];
                else
                    ((fp16*)Cout)[(size_t)row * Nout + col] = (fp16)acc[m][n][r];
            }
}

// ---------------- causal flash attention, SWAPPED QK^T (scores transposed: lane owns q-row) ----
// sc = mfma(K_frag, Q_frag): lane (lr,lg) reg r holds S[kv=kv0+f*16+lg*4+r][q=qr0+lr], log2 units
// (0.125*log2e folded into Q at rope). m/lsum scalar per lane. P packed b64 into swizzled LDS.
// grid (1024): head = bx & 31; grp = bx>>5; qt = {31-a, 8+a, 23-a, a}[grp>>3], a=grp&7 (bijective).
__global__ __launch_bounds__(256) void attn_kernel(
    const fp16* __restrict__ qb, const fp16* __restrict__ kb,
    const fp16* __restrict__ vt, fp16* __restrict__ o_all) {
    __shared__ fp16 Kb[2][64][64];  // 16 KB (16B-chunk XOR swizzled)
    __shared__ fp16 Vb[2][64][64];  // 16 KB (swizzled)
    __shared__ fp16 P[4][16][64];   //  8 KB per-wave [q=lr][kv], b64-group swizzled -> 40960 B
    const int t = threadIdx.x, wid = t >> 6, lane = t & 63;
    const int bx = blockIdx.x;
    const int grp = bx >> 5;
    const int a = grp & 7;
    const int sel = grp >> 3;
    const int qt = (sel == 0) ? (31 - a) : (sel == 1) ? (8 + a) : (sel == 2) ? (23 - a) : a;
    const int head = bx & 31;
    const int g = head >> 2;
    const int lr = lane & 15, lg = lane >> 4;
    const fp16* qh = qb + (size_t)head * SEQ * HD;
    const fp16* kh = kb + (size_t)g * SEQ * HD;
    const fp16* vh = vt + (size_t)g * HD * SEQ;
    const int srow = lane >> 3, schunk = lane & 7;
    const int qr0 = qt * 64 + wid * 16;
    char* pb = (char*)&P[wid][0][0];

    half8 aq0 = *reinterpret_cast<const half8*>(qh + (size_t)(qr0 + lr) * HD + lg * 8);
    half8 aq1 = *reinterpret_cast<const half8*>(qh + (size_t)(qr0 + lr) * HD + 32 + lg * 8);
    f32x4 o[4] = {};
    float m_ = -1e30f, lsum_ = 0.0f;  // per-lane: q = qr0 + lr (lane-partial over kv groups)
    const int nt = qt + 1;

    auto stage = [&](int kt, int b) {
        const int kv0 = kt << 6;
#pragma unroll
        for (int i = 0; i < 2; ++i) {
            int row = wid * 16 + i * 8 + srow;
            int sw = (schunk ^ srow) * 8;
            gll16(kh + (size_t)(kv0 + row) * HD + sw, &Kb[b][wid * 16 + i * 8][0]);
            gll16(vh + (size_t)row * SEQ + kv0 + sw, &Vb[b][wid * 16 + i * 8][0]);
        }
    };

    stage(0, 0);
    __syncthreads();
    for (int tt = 0; tt < nt; ++tt) {
        const int cur = tt & 1;
        if (tt + 1 < nt) stage(tt + 1, cur ^ 1);
        const int kv0 = tt << 6;
        f32x4 sc[4];
        __builtin_amdgcn_s_setprio(1);
#pragma unroll
        for (int f = 0; f < 4; ++f) {
            int row = f * 16 + lr;
            const char* kbp = (const char*)&Kb[cur][row][0];
            half8 b0 = *(const half8*)(kbp + (((lg) ^ (row & 7)) * 16));
            half8 b1 = *(const half8*)(kbp + (((4 + lg) ^ (row & 7)) * 16));
            f32x4 s = {};
            s = __builtin_amdgcn_mfma_f32_16x16x32_f16(b0, aq0, s, 0, 0, 0);  // swapped
            s = __builtin_amdgcn_mfma_f32_16x16x32_f16(b1, aq1, s, 0, 0, 0);
            sc[f] = s;
        }
        __builtin_amdgcn_s_setprio(0);
        if (tt == qt) {
            const int q = qr0 + lr;
#pragma unroll
            for (int f = 0; f < 4; f++)
#pragma unroll
                for (int r = 0; r < 4; r++) {
                    int kv = kv0 + f * 16 + lg * 4 + r;
                    if (kv > q) sc[f][r] = -1e30f;
                }
        }
        // ---- defer-max (log2 domain, threshold 11): lane-local over all 16 values ----
        float lmax = sc[0][0];
#pragma unroll
        for (int f = 0; f < 4; f++)
#pragma unroll
            for (int r = 0; r < 4; r++) lmax = fmaxf(lmax, sc[f][r]);
        if (!__all(lmax <= m_ + 11.0f)) {  // rare: reduce across the 4 kv-group lanes of each q
            float v = lmax;
            v = fmaxf(v, __shfl_xor(v, 16));
            v = fmaxf(v, __shfl_xor(v, 32));
            float mn = fmaxf(m_, v);
            float alpha = exp2f(m_ - mn);
            m_ = mn;
            lsum_ *= alpha;
            // o[vf][r] is q = qr0 + lg*4 + r -> alpha lives in lane lg*4+r
            float al[4];
#pragma unroll
            for (int r = 0; r < 4; r++) al[r] = __shfl(alpha, lg * 4 + r);
#pragma unroll
            for (int vf = 0; vf < 4; vf++)
#pragma unroll
                for (int r = 0; r < 4; r++) o[vf][r] *= al[r];
        }
        // ---- exp2, lane-partial lsum, pack pairs, 4 swizzled b64 P-writes ----
#pragma unroll
        for (int f = 0; f < 4; f++) {
            float p0 = exp2f(sc[f][0] - m_);
            float p1 = exp2f(sc[f][1] - m_);
            float p2 = exp2f(sc[f][2] - m_);
            float p3 = exp2f(sc[f][3] - m_);
            lsum_ += (p0 + p1) + (p2 + p3);
            fp16raw2 k0 = __builtin_amdgcn_cvt_pkrtz(p0, p1);
            fp16raw2 k1 = __builtin_amdgcn_cvt_pkrtz(p2, p3);
            uint2 w;
            w.x = __builtin_bit_cast(unsigned int, k0);
            w.y = __builtin_bit_cast(unsigned int, k1);
            *(uint2*)(pb + lr * 128 + ((f * 32 + lg * 8) ^ ((lr & 7) << 4))) = w;
        }
        // ---- PV: pa = A-frag of P (row=q=lr, k=kv=h*32+lg*8+b) ----
        __builtin_amdgcn_s_setprio(1);
#pragma unroll
        for (int h = 0; h < 2; h++) {
            half8 pa = *(const half8*)(pb + lr * 128 + (((h * 4 + lg) ^ (lr & 7)) * 16));
#pragma unroll
            for (int vf = 0; vf < 4; vf++) {
                int d = vf * 16 + lr;
                int xo = ((h * 4 + lg) ^ (d & 7)) * 16;
                half8 bv = *(const half8*)((const char*)&Vb[cur][d][0] + xo);
                o[vf] = __builtin_amdgcn_mfma_f32_16x16x32_f16(pa, bv, o[vf], 0, 0, 0);
            }
        }
        __builtin_amdgcn_s_setprio(0);
        __syncthreads();  // drains vmcnt (stage of tt+1) + protects buffer reuse
    }
    // final: reduce lsum across kv-group lanes, broadcast to (lg,r) indexing, write
    lsum_ += __shfl_xor(lsum_, 16);
    lsum_ += __shfl_xor(lsum_, 32);
    float li[4];
#pragma unroll
    for (int r = 0; r < 4; r++) li[r] = 1.0f / __shfl(lsum_, lg * 4 + r);
#pragma unroll
    for (int vf = 0; vf < 4; vf++)
#pragma unroll
        for (int r = 0; r < 4; r++) {
            float v = o[vf][r] * li[r];
            o_all[(size_t)(qr0 + lg * 4 + r) * 2048 + head * 64 + vf * 16 + lr] = (fp16)v;
        }
}

extern "C" void kernel_launch(void* const* d_in, const int* in_sizes, int n_in,
                              void* d_out, int out_size, void* d_ws, size_t ws_size,
                              hipStream_t stream) {
    const float* x  = (const float*)d_in[0];
    const float* wq = (const float*)d_in[1];
    const float* wk = (const float*)d_in[2];
    const float* wv = (const float*)d_in[3];
    const float* wo = (const float*)d_in[4];
    float* out = (float*)d_out;
    char* ws = (char*)d_ws;

    // Workspace (52 MB peak). o_all aliases proj (dead after rope_vt). w2t separate
    // (prep writes it before gemm_proj, so it must not alias xh).
    fp16* xh    = (fp16*)(ws);                        // 8 MB  [2048][2048]
    fp16* wqkvt = (fp16*)(ws + ((size_t)8 << 20));    // 12 MB [3072][2048] ([48][64][2048])
    fp16* proj  = (fp16*)(ws + ((size_t)20 << 20));   // 12 MB [2048][3072]
    fp16* o_all = proj;                               // alias (8 MB)
    fp16* w2t   = (fp16*)(ws + ((size_t)32 << 20));   // 8 MB  [2048 d][2048 hv]
    fp16* qbuf  = (fp16*)(ws + ((size_t)40 << 20));   // 8 MB  [32][2048][64]
    fp16* kbuf  = (fp16*)(ws + ((size_t)48 << 20));   // 2 MB  [8][2048][64]
    fp16* vtb   = (fp16*)(ws + ((size_t)50 << 20));   // 2 MB  [8][64][2048]

    prep_kernel<<<dim3(3584), 256, 0, stream>>>(x, wq, wk, wv, wo, xh, wqkvt, w2t);
    gemm_tpl<64, 128, 0><<<dim3(32, 24), 256, 0, stream>>>(xh, wqkvt, proj, 3072);
    rope_vt_kernel<<<dim3(10496), 256, 0, stream>>>(proj, qbuf, kbuf, vtb);
    attn_kernel<<<dim3(1024), 256, 0, stream>>>(qbuf, kbuf, vtb, o_all);
    gemm_tpl<64, 128, 1><<<dim3(32, 16), 256, 0, stream>>>(o_all, w2t, out, 2048);
}